// Round 1
// baseline (1018.566 us; speedup 1.0000x reference)
//
#include <hip/hip_runtime.h>

// Problem constants (match reference setup_inputs)
#define NB    50000   // nodes
#define BB    64      // batch  (== wavefront size: lane = b)
#define DD    16      // neighbors per node
#define NDRVN 1000    // driver nodes

typedef float f2 __attribute__((ext_vector_type(2)));
typedef float f4 __attribute__((ext_vector_type(4)));

// ---------------------------------------------------------------------------
// relu on a packed pair -> v_pk_max_f32
__device__ __forceinline__ f2 relu2(f2 a) {
    return __builtin_elementwise_max(a, (f2)0.0f);
}

// ---------------------------------------------------------------------------
// VOP3P op_sel broadcast FMAs.
// Weights stay packed 2-per-64b-register exactly as in memory; op_sel/op_sel_hi
// pick one half of the weight pair (and of the bias pair for the first tap)
// and broadcast it to both halves of the result.  Weight cost: 1 VGPR/weight,
// zero splat movs.  Data (in/acc) use default packed behavior.
//
// acc += w.lo * in      (src0 lo -> both halves)
__device__ __forceinline__ void fma_wlo(f2 w, f2 in, f2& acc) {
    asm("v_pk_fma_f32 %0, %1, %2, %0 op_sel_hi:[0,1,1]"
        : "+v"(acc) : "v"(w), "v"(in));
}
// acc += w.hi * in      (src0 hi -> both halves)
__device__ __forceinline__ void fma_whi(f2 w, f2 in, f2& acc) {
    asm("v_pk_fma_f32 %0, %1, %2, %0 op_sel:[1,0,0] op_sel_hi:[1,1,1]"
        : "+v"(acc) : "v"(w), "v"(in));
}
// d = w.lo * in + b.lo
__device__ __forceinline__ f2 fma_wb_ll(f2 w, f2 in, f2 b) {
    f2 d;
    asm("v_pk_fma_f32 %0, %1, %2, %3 op_sel_hi:[0,1,0]"
        : "=v"(d) : "v"(w), "v"(in), "v"(b));
    return d;
}
// d = w.lo * in + b.hi
__device__ __forceinline__ f2 fma_wb_lh(f2 w, f2 in, f2 b) {
    f2 d;
    asm("v_pk_fma_f32 %0, %1, %2, %3 op_sel:[0,0,1] op_sel_hi:[0,1,1]"
        : "=v"(d) : "v"(w), "v"(in), "v"(b));
    return d;
}
// d = w.hi * in + b.lo
__device__ __forceinline__ f2 fma_wb_hl(f2 w, f2 in, f2 b) {
    f2 d;
    asm("v_pk_fma_f32 %0, %1, %2, %3 op_sel:[1,0,0] op_sel_hi:[1,1,0]"
        : "=v"(d) : "v"(w), "v"(in), "v"(b));
    return d;
}
// d = w.hi * in + b.hi
__device__ __forceinline__ f2 fma_wb_hh(f2 w, f2 in, f2 b) {
    f2 d;
    asm("v_pk_fma_f32 %0, %1, %2, %3 op_sel:[1,0,1] op_sel_hi:[1,1,1]"
        : "=v"(d) : "v"(w), "v"(in), "v"(b));
    return d;
}

// j is a compile-time constant after full unrolling -> branch folds away.
__device__ __forceinline__ void conv_step(const f2* wp, int j, f2 in, f2& acc) {
    if (j & 1) fma_whi(wp[j >> 1], in, acc);
    else       fma_wlo(wp[j >> 1], in, acc);
}
// first tap: fold the bias into src2 via op_sel (no bias splat, no init mov)
__device__ __forceinline__ f2 conv_begin(const f2* wp, int jw, const f2* bp,
                                         int jb, f2 in) {
    f2 w = wp[jw >> 1], b = bp[jb >> 1];
    if (jw & 1) return (jb & 1) ? fma_wb_hh(w, in, b) : fma_wb_hl(w, in, b);
    else        return (jb & 1) ? fma_wb_lh(w, in, b) : fma_wb_ll(w, in, b);
}

// ---------------------------------------------------------------------------
// Weight loads: force VECTOR loads into VGPRs (not s_load + v_mov splats) by
// indexing with a VGPR the compiler can't prove uniform/zero.
// All lanes load the same address -> coalesces to one line, L1-hot.
__device__ __forceinline__ void load_w75(const float* __restrict__ w,
                                         const float* __restrict__ b,
                                         int vz, f2 (&wp)[38], f2 (&bp)[3]) {
    const f4* w4 = (const f4*)w;
#pragma unroll
    for (int i = 0; i < 18; ++i) {      // floats 0..71
        f4 t = w4[vz + i];
        wp[2 * i]     = (f2){t.x, t.y};  // sub-register extract, no movs
        wp[2 * i + 1] = (f2){t.z, t.w};
    }
    wp[36] = ((const f2*)w)[vz + 36];   // floats 72,73
    wp[37] = (f2){w[vz + 74], 0.0f};    // float 74 (hi unused)
    f4 tb = ((const f4*)b)[vz];         // 5-float bias: 16B + 4B
    bp[0] = (f2){tb.x, tb.y};
    bp[1] = (f2){tb.z, tb.w};
    bp[2] = (f2){b[vz + 4], 0.0f};
}

__device__ __forceinline__ void load_w15(const float* __restrict__ w,
                                         const float* __restrict__ b, int nb,
                                         int vz, f2 (&wp)[8], f2 (&bp)[3]) {
    const f4* w4 = (const f4*)w;
#pragma unroll
    for (int i = 0; i < 3; ++i) {       // floats 0..11
        f4 t = w4[vz + i];
        wp[2 * i]     = (f2){t.x, t.y};
        wp[2 * i + 1] = (f2){t.z, t.w};
    }
    wp[6] = ((const f2*)w)[vz + 6];     // 12,13
    wp[7] = (f2){w[vz + 14], 0.0f};     // 14
    if (nb == 5) {
        f4 tb = ((const f4*)b)[vz];
        bp[0] = (f2){tb.x, tb.y};
        bp[1] = (f2){tb.z, tb.w};
        bp[2] = (f2){b[vz + 4], 0.0f};
    } else {
        bp[0] = (f2){b[vz + 0], 0.0f};
        bp[1] = (f2){0.0f, 0.0f};
        bp[2] = (f2){0.0f, 0.0f};
    }
}

// ---------------------------------------------------------------------------
// Transpose x (B,N) -> z0 (N,B).
__global__ __launch_bounds__(256) void transpose_kernel(
    const float* __restrict__ x, float* __restrict__ xT)
{
    int tid = blockIdx.x * 256 + threadIdx.x;   // tid = n*64 + b
    int n = tid >> 6;
    int b = tid & 63;
    if (n < NB) xT[tid] = x[b * NB + n];
}

// ---------------------------------------------------------------------------
// One 5->5 conv1x3+relu layer for TWO nodes packed as f2 (.x=node A, .y=B).
// x-outer / channel-inner: in-columns die as out-columns are produced ->
// data liveness stays ~5*WIN f2 + 41 weight/bias pairs.
template<int WIN>
__device__ __forceinline__ void conv5p(const f2 (&in)[5][14], f2 (&out)[5][14],
                                       const f2 (&wp)[38], const f2 (&bp)[3])
{
    constexpr int WOUT = WIN - 2;
#pragma unroll
    for (int x = 0; x < WOUT; ++x) {
#pragma unroll
        for (int c = 0; c < 5; ++c) {
            const int j0 = c * 15;      // w[co][ci][t] flat index; 15 is odd ->
                                        // parity alternates per c, folded at CT
            f2 acc = conv_begin(wp, j0, bp, c, in[0][x]);
            conv_step(wp, j0 + 1, in[0][x + 1], acc);
            conv_step(wp, j0 + 2, in[0][x + 2], acc);
#pragma unroll
            for (int ci = 1; ci < 5; ++ci) {
#pragma unroll
                for (int t = 0; t < 3; ++t)
                    conv_step(wp, j0 + ci * 3 + t, in[ci][x + t], acc);
            }
            out[c][x] = relu2(acc);
        }
    }
}

// ---------------------------------------------------------------------------
// One full pass, TWO nodes per wave packed into f2 lanes.
// waves_per_eu(2,2): target exactly 2 waves/SIMD so the allocator may use up
// to 256 VGPRs -> peak liveness (~140 data + ~82 weights) fits, no spills.
__global__ __launch_bounds__(256)
__attribute__((amdgpu_waves_per_eu(2, 2)))
void pass_kernel(
    const float* __restrict__ zin, float* __restrict__ zout,
    const int*  __restrict__ nidx,
    const float* __restrict__ w0, const float* __restrict__ b0,
    const float* __restrict__ w1, const float* __restrict__ b1,
    const float* __restrict__ w2, const float* __restrict__ b2,
    const float* __restrict__ w3, const float* __restrict__ b3,
    const float* __restrict__ w4, const float* __restrict__ b4,
    const float* __restrict__ w5, const float* __restrict__ b5,
    const float* __restrict__ w6, const float* __restrict__ b6)
{
    int lane   = threadIdx.x & 63;
    int waveid = blockIdx.x * 4 + (threadIdx.x >> 6);     // 25000 waves
    int n0 = __builtin_amdgcn_readfirstlane(waveid * 2);  // nodes n0, n0+1

    int vz;
    asm("v_mov_b32 %0, 0" : "=v"(vz));   // VGPR zero, opaque to uniformity

    // Neighbor indices for both nodes: 32 contiguous ints -> s_loads.
    const int* ip = nidx + n0 * DD;

    // Gather both nodes' neighborhoods into f2 pairs (.x = A, .y = B).
    f2 g[16];
#pragma unroll
    for (int d = 0; d < 16; ++d) {
        float a = zin[(size_t)ip[d]      * BB + lane];
        float b = zin[(size_t)ip[16 + d] * BB + lane];
        g[d] = (f2){a, b};
    }

    f2 ha[5][14], hb[5][14];

    // Layer 0: 1 -> 5 channels, width 16 -> 14
    {
        f2 wp[8], bp[3];
        load_w15(w0, b0, 5, vz, wp, bp);
#pragma unroll
        for (int x = 0; x < 14; ++x) {
#pragma unroll
            for (int c = 0; c < 5; ++c) {
                const int j0 = c * 3;
                f2 acc = conv_begin(wp, j0, bp, c, g[x]);
                conv_step(wp, j0 + 1, g[x + 1], acc);
                conv_step(wp, j0 + 2, g[x + 2], acc);
                ha[c][x] = relu2(acc);
            }
        }
    }

    { f2 wp[38], bp[3]; load_w75(w1, b1, vz, wp, bp); conv5p<14>(ha, hb, wp, bp); }
    { f2 wp[38], bp[3]; load_w75(w2, b2, vz, wp, bp); conv5p<12>(hb, ha, wp, bp); }
    { f2 wp[38], bp[3]; load_w75(w3, b3, vz, wp, bp); conv5p<10>(ha, hb, wp, bp); }
    { f2 wp[38], bp[3]; load_w75(w4, b4, vz, wp, bp); conv5p<8> (hb, ha, wp, bp); }
    { f2 wp[38], bp[3]; load_w75(w5, b5, vz, wp, bp); conv5p<6> (ha, hb, wp, bp); }

    // Layer 6: 5 -> 1, width 4 -> 2, then pair-average.
    {
        f2 wp[8], bp[3];
        load_w15(w6, b6, 1, vz, wp, bp);
        f2 t0 = conv_begin(wp, 0, bp, 0, hb[0][0]);
        f2 t1 = conv_begin(wp, 0, bp, 0, hb[0][1]);
        conv_step(wp, 1, hb[0][1], t0);
        conv_step(wp, 2, hb[0][2], t0);
        conv_step(wp, 1, hb[0][2], t1);
        conv_step(wp, 2, hb[0][3], t1);
#pragma unroll
        for (int ci = 1; ci < 5; ++ci) {
#pragma unroll
            for (int t = 0; t < 3; ++t) {
                conv_step(wp, ci * 3 + t, hb[ci][0 + t], t0);
                conv_step(wp, ci * 3 + t, hb[ci][1 + t], t1);
            }
        }
        t0 = relu2(t0);
        t1 = relu2(t1);
        f2 o = (t0 + t1) * 0.5f;
        zout[(size_t)n0 * BB + lane]       = o.x;
        zout[(size_t)(n0 + 1) * BB + lane] = o.y;
    }
}

// ---------------------------------------------------------------------------
// Final driver gather: out[b, i] = z[driver_idx[i], b]   (out is (B, NDRV))
__global__ __launch_bounds__(256) void gather_out_kernel(
    const float* __restrict__ z, const int* __restrict__ didx,
    float* __restrict__ out)
{
    int i = blockIdx.x * 256 + threadIdx.x;
    if (i >= BB * NDRVN) return;
    int b = i / NDRVN;
    int k = i - b * NDRVN;
    out[i] = z[(size_t)didx[k] * BB + b];
}

// ---------------------------------------------------------------------------
extern "C" void kernel_launch(void* const* d_in, const int* in_sizes, int n_in,
                              void* d_out, int out_size, void* d_ws, size_t ws_size,
                              hipStream_t stream)
{
    const float* x    = (const float*)d_in[0];
    const int*   nidx = (const int*)  d_in[1];
    const int*   didx = (const int*)  d_in[2];
    const float* w[7];
    const float* b[7];
    for (int i = 0; i < 7; ++i) {
        w[i] = (const float*)d_in[3 + 2 * i];
        b[i] = (const float*)d_in[4 + 2 * i];
    }

    // Workspace: two ping-pong z buffers in (N, B) layout, 12.8 MB each.
    float* z0 = (float*)d_ws;
    float* z1 = z0 + (size_t)NB * BB;

    const int tblocks = (NB * BB) / 256;   // 12500 (transpose)
    const int pblocks = NB / 8;            // 6250: 4 waves x 2 nodes

    transpose_kernel<<<tblocks, 256, 0, stream>>>(x, z0);

    pass_kernel<<<pblocks, 256, 0, stream>>>(z0, z1, nidx,
        w[0], b[0], w[1], b[1], w[2], b[2], w[3], b[3],
        w[4], b[4], w[5], b[5], w[6], b[6]);
    pass_kernel<<<pblocks, 256, 0, stream>>>(z1, z0, nidx,
        w[0], b[0], w[1], b[1], w[2], b[2], w[3], b[3],
        w[4], b[4], w[5], b[5], w[6], b[6]);
    pass_kernel<<<pblocks, 256, 0, stream>>>(z0, z1, nidx,
        w[0], b[0], w[1], b[1], w[2], b[2], w[3], b[3],
        w[4], b[4], w[5], b[5], w[6], b[6]);
    pass_kernel<<<pblocks, 256, 0, stream>>>(z1, z0, nidx,
        w[0], b[0], w[1], b[1], w[2], b[2], w[3], b[3],
        w[4], b[4], w[5], b[5], w[6], b[6]);

    gather_out_kernel<<<(BB * NDRVN + 255) / 256, 256, 0, stream>>>(z0, didx, (float*)d_out);
}